// Round 1
// baseline (253.366 us; speedup 1.0000x reference)
//
#include <hip/hip_runtime.h>

#define NN 8192

// Kernel 1: per-row sum -> d[row] = rsqrt(sum), inf->0
__global__ __launch_bounds__(256) void rowsum_rsqrt_kernel(
    const float* __restrict__ A, float* __restrict__ d) {
    const int row = blockIdx.x;
    const float4* Arow = reinterpret_cast<const float4*>(A + (size_t)row * NN);
    float s = 0.f;
    // 2048 float4 per row, 256 threads -> 8 each, coalesced stride
    for (int k = threadIdx.x; k < NN / 4; k += 256) {
        float4 v = Arow[k];
        s += (v.x + v.y) + (v.z + v.w);
    }
    // wave (64-lane) reduction
    #pragma unroll
    for (int off = 32; off > 0; off >>= 1)
        s += __shfl_down(s, off, 64);
    __shared__ float ls[4];
    const int lane = threadIdx.x & 63;
    const int wid  = threadIdx.x >> 6;
    if (lane == 0) ls[wid] = s;
    __syncthreads();
    if (threadIdx.x == 0) {
        float t = (ls[0] + ls[1]) + (ls[2] + ls[3]);
        d[row] = (t > 0.f) ? (1.0f / sqrtf(t)) : 0.f;
    }
}

// Kernel 2: elementwise build of Lfilter (= DAD), Hfilter (= 2I - DAD), and
// passthrough of A. float4-vectorized; one float4 per thread.
__global__ __launch_bounds__(256) void build_filters_kernel(
    const float* __restrict__ A, const float* __restrict__ d,
    float* __restrict__ lf, float* __restrict__ hf, float* __restrict__ ga) {
    const size_t idx = (size_t)blockIdx.x * 256 + threadIdx.x; // float4 index
    const int i  = (int)(idx >> 11);          // row: 2048 float4 per row
    const int j4 = (int)(idx & 2047);         // float4-col
    const int j  = j4 * 4;

    float4 a  = reinterpret_cast<const float4*>(A)[idx];
    float  di = d[i];
    float4 dj = reinterpret_cast<const float4*>(d)[j4];

    float4 dad;
    dad.x = di * a.x * dj.x;
    dad.y = di * a.y * dj.y;
    dad.z = di * a.z * dj.z;
    dad.w = di * a.w * dj.w;

    float4 h;
    h.x = ((j + 0) == i ? 2.0f : 0.0f) - dad.x;
    h.y = ((j + 1) == i ? 2.0f : 0.0f) - dad.y;
    h.z = ((j + 2) == i ? 2.0f : 0.0f) - dad.z;
    h.w = ((j + 3) == i ? 2.0f : 0.0f) - dad.w;

    reinterpret_cast<float4*>(lf)[idx] = dad;
    reinterpret_cast<float4*>(hf)[idx] = h;
    reinterpret_cast<float4*>(ga)[idx] = a;
}

extern "C" void kernel_launch(void* const* d_in, const int* in_sizes, int n_in,
                              void* d_out, int out_size, void* d_ws, size_t ws_size,
                              hipStream_t stream) {
    const float* A = (const float*)d_in[0];
    float* out = (float*)d_out;
    const size_t M = (size_t)NN * NN;
    float* lf = out;           // Lfilter = DAD
    float* hf = out + M;       // Hfilter = 2I - DAD
    float* ga = out + 2 * M;   // Graph_adj passthrough
    float* d  = (float*)d_ws;  // 8192 floats

    rowsum_rsqrt_kernel<<<NN, 256, 0, stream>>>(A, d);

    const int nblocks = (int)(M / 4 / 256);  // 65536
    build_filters_kernel<<<nblocks, 256, 0, stream>>>(A, d, lf, hf, ga);
}

// Round 3
// 196.889 us; speedup vs baseline: 1.2868x; 1.2868x over previous
//
#include <hip/hip_runtime.h>

#define NN 8192

typedef float f32x4 __attribute__((ext_vector_type(4)));

// Kernel 1: per-row sum -> d[row] = rsqrt(sum) (inf->0), AND stream the
// passthrough copy of A to ga. Regular loads (populate L3 with A),
// non-temporal stores (don't let the copy evict A).
__global__ __launch_bounds__(256) void rowsum_copy_kernel(
    const float* __restrict__ A, float* __restrict__ d, float* __restrict__ ga) {
    const int row = blockIdx.x;
    const f32x4* Arow = reinterpret_cast<const f32x4*>(A + (size_t)row * NN);
    f32x4*       Grow = reinterpret_cast<f32x4*>(ga + (size_t)row * NN);
    float s = 0.f;
    // 2048 f32x4 per row, 256 threads -> 8 each, coalesced
    for (int k = threadIdx.x; k < NN / 4; k += 256) {
        f32x4 v = Arow[k];
        __builtin_nontemporal_store(v, &Grow[k]);
        s += (v.x + v.y) + (v.z + v.w);
    }
    #pragma unroll
    for (int off = 32; off > 0; off >>= 1)
        s += __shfl_down(s, off, 64);
    __shared__ float ls[4];
    const int lane = threadIdx.x & 63;
    const int wid  = threadIdx.x >> 6;
    if (lane == 0) ls[wid] = s;
    __syncthreads();
    if (threadIdx.x == 0) {
        float t = (ls[0] + ls[1]) + (ls[2] + ls[3]);
        d[row] = (t > 0.f) ? (1.0f / sqrtf(t)) : 0.f;
    }
}

// Kernel 2: Lfilter (= DAD) and Hfilter (= 2I - DAD). Reads A (hopefully
// L3-resident from kernel 1), non-temporal stores for both outputs.
// Block order reversed so we start with the rows most recently streamed.
__global__ __launch_bounds__(256) void build_filters_kernel(
    const float* __restrict__ A, const float* __restrict__ d,
    float* __restrict__ lf, float* __restrict__ hf, int nblocks) {
    const size_t idx = (size_t)(nblocks - 1 - blockIdx.x) * 256 + threadIdx.x; // f32x4 index
    const int i  = (int)(idx >> 11);          // row: 2048 f32x4 per row (uniform per block)
    const int j4 = (int)(idx & 2047);
    const int j  = j4 * 4;

    f32x4 a  = reinterpret_cast<const f32x4*>(A)[idx];
    float di = d[i];
    f32x4 dj = reinterpret_cast<const f32x4*>(d)[j4];

    f32x4 dad = di * a * dj;

    f32x4 h;
    h.x = ((j + 0) == i ? 2.0f : 0.0f) - dad.x;
    h.y = ((j + 1) == i ? 2.0f : 0.0f) - dad.y;
    h.z = ((j + 2) == i ? 2.0f : 0.0f) - dad.z;
    h.w = ((j + 3) == i ? 2.0f : 0.0f) - dad.w;

    __builtin_nontemporal_store(dad, &reinterpret_cast<f32x4*>(lf)[idx]);
    __builtin_nontemporal_store(h,   &reinterpret_cast<f32x4*>(hf)[idx]);
}

extern "C" void kernel_launch(void* const* d_in, const int* in_sizes, int n_in,
                              void* d_out, int out_size, void* d_ws, size_t ws_size,
                              hipStream_t stream) {
    const float* A = (const float*)d_in[0];
    float* out = (float*)d_out;
    const size_t M = (size_t)NN * NN;
    float* lf = out;           // Lfilter = DAD
    float* hf = out + M;       // Hfilter = 2I - DAD
    float* ga = out + 2 * M;   // Graph_adj passthrough
    float* d  = (float*)d_ws;  // 8192 floats

    rowsum_copy_kernel<<<NN, 256, 0, stream>>>(A, d, ga);

    const int nblocks = (int)(M / 4 / 256);  // 65536
    build_filters_kernel<<<nblocks, 256, 0, stream>>>(A, d, lf, hf, nblocks);
}

// Round 4
// 192.072 us; speedup vs baseline: 1.3191x; 1.0251x over previous
//
#include <hip/hip_runtime.h>

#define NN 8192

typedef float f32x4 __attribute__((ext_vector_type(4)));

// Kernel 1: PURE READ. Per-row sum -> d[row] = rsqrt(sum) (inf->0).
// Seeds L3 with all of A with no write interference. One block per row,
// 8 float4/thread fully unrolled (burst loads).
__global__ __launch_bounds__(256) void rowsum_kernel(
    const float* __restrict__ A, float* __restrict__ d) {
    const int row = blockIdx.x;
    const f32x4* Arow = reinterpret_cast<const f32x4*>(A + (size_t)row * NN);
    f32x4 v[8];
    #pragma unroll
    for (int u = 0; u < 8; ++u)
        v[u] = Arow[threadIdx.x + 256 * u];
    float s = 0.f;
    #pragma unroll
    for (int u = 0; u < 8; ++u)
        s += (v[u].x + v[u].y) + (v[u].z + v[u].w);
    #pragma unroll
    for (int off = 32; off > 0; off >>= 1)
        s += __shfl_down(s, off, 64);
    __shared__ float ls[4];
    const int lane = threadIdx.x & 63;
    const int wid  = threadIdx.x >> 6;
    if (lane == 0) ls[wid] = s;
    __syncthreads();
    if (threadIdx.x == 0) {
        float t = (ls[0] + ls[1]) + (ls[2] + ls[3]);
        d[row] = (t > 0.f) ? (1.0f / sqrtf(t)) : 0.f;
    }
}

// Kernel 2: PURE HBM WRITE (A read should hit L3). Builds Lfilter (= DAD),
// Hfilter (= 2I - DAD), and the Graph_adj passthrough. All stores
// non-temporal (keep A resident in L3). 2 float4/thread in 256-apart chunks:
// every instruction perfectly coalesced; loads grouped before stores.
// Block order reversed so the first blocks read the most recently cached rows.
__global__ __launch_bounds__(256) void build_filters_kernel(
    const float* __restrict__ A, const float* __restrict__ d,
    float* __restrict__ lf, float* __restrict__ hf, float* __restrict__ ga,
    int nblocks) {
    const size_t base = (size_t)(nblocks - 1 - blockIdx.x) * 512; // f32x4 units
    const size_t idx0 = base + threadIdx.x;
    const size_t idx1 = idx0 + 256;
    const int i = (int)(base >> 11);      // row (512 | 2048 -> uniform per block)
    const float di = d[i];                // scalar (block-uniform) load

    const f32x4* A4 = reinterpret_cast<const f32x4*>(A);
    const f32x4* d4 = reinterpret_cast<const f32x4*>(d);

    f32x4 a0 = A4[idx0];
    f32x4 a1 = A4[idx1];
    f32x4 dj0 = d4[idx0 & 2047];
    f32x4 dj1 = d4[idx1 & 2047];

    f32x4 dad0 = di * a0 * dj0;
    f32x4 dad1 = di * a1 * dj1;

    const int j0 = (int)(idx0 & 2047) * 4;
    const int j1 = (int)(idx1 & 2047) * 4;
    f32x4 h0, h1;
    h0.x = ((j0 + 0) == i ? 2.0f : 0.0f) - dad0.x;
    h0.y = ((j0 + 1) == i ? 2.0f : 0.0f) - dad0.y;
    h0.z = ((j0 + 2) == i ? 2.0f : 0.0f) - dad0.z;
    h0.w = ((j0 + 3) == i ? 2.0f : 0.0f) - dad0.w;
    h1.x = ((j1 + 0) == i ? 2.0f : 0.0f) - dad1.x;
    h1.y = ((j1 + 1) == i ? 2.0f : 0.0f) - dad1.y;
    h1.z = ((j1 + 2) == i ? 2.0f : 0.0f) - dad1.z;
    h1.w = ((j1 + 3) == i ? 2.0f : 0.0f) - dad1.w;

    f32x4* lf4 = reinterpret_cast<f32x4*>(lf);
    f32x4* hf4 = reinterpret_cast<f32x4*>(hf);
    f32x4* ga4 = reinterpret_cast<f32x4*>(ga);
    __builtin_nontemporal_store(dad0, &lf4[idx0]);
    __builtin_nontemporal_store(dad1, &lf4[idx1]);
    __builtin_nontemporal_store(h0,   &hf4[idx0]);
    __builtin_nontemporal_store(h1,   &hf4[idx1]);
    __builtin_nontemporal_store(a0,   &ga4[idx0]);
    __builtin_nontemporal_store(a1,   &ga4[idx1]);
}

extern "C" void kernel_launch(void* const* d_in, const int* in_sizes, int n_in,
                              void* d_out, int out_size, void* d_ws, size_t ws_size,
                              hipStream_t stream) {
    const float* A = (const float*)d_in[0];
    float* out = (float*)d_out;
    const size_t M = (size_t)NN * NN;
    float* lf = out;           // Lfilter = DAD
    float* hf = out + M;       // Hfilter = 2I - DAD
    float* ga = out + 2 * M;   // Graph_adj passthrough
    float* d  = (float*)d_ws;  // 8192 floats

    rowsum_kernel<<<NN, 256, 0, stream>>>(A, d);

    const int nblocks = (int)(M / 4 / 512);  // 32768
    build_filters_kernel<<<nblocks, 256, 0, stream>>>(A, d, lf, hf, ga, nblocks);
}